// Round 14
// baseline (232.119 us; speedup 1.0000x reference)
//
#include <hip/hip_runtime.h>

#define BSEG   16384
#define NPART  256
#define CHUNK  4
// ws layout (proven to fit): seg_in[BSEG] f32, seg_tg[BSEG] f32, elem_part[NPART] f64
#define WS_BYTES (2 * BSEG * 4 + NPART * 8)

__global__ __launch_bounds__(256) void main_pass(
        const float* __restrict__ in, const float* __restrict__ tg,
        const int* __restrict__ batch,
        float* __restrict__ seg_in, float* __restrict__ seg_tg,
        double* __restrict__ elem_part, int n)
{
    const int tid  = blockIdx.x * blockDim.x + threadIdx.x;
    const int lane = threadIdx.x & 63;
    const long long i0 = (long long)tid * CHUNK;
    const bool live = (i0 < n);          // N divisible by 4 => full chunks

    // ---- exactly the m13 µbench access shape: 16 B/lane/instr per stream ----
    float4 a, t; int4 c;
    if (live) {
        a = *reinterpret_cast<const float4*>(in + i0);
        t = *reinterpret_cast<const float4*>(tg + i0);
        c = *reinterpret_cast<const int4*>(batch + i0);
    }

    float elem = 0.0f;
    int   cur  = -1;                     // dead lanes: sentinel, zero sums
    float si = 0.0f, st = 0.0f;

    if (live) {
        float vi[CHUNK] = {a.x, a.y, a.z, a.w};
        float vt[CHUNK] = {t.x, t.y, t.z, t.w};
        int   vb[CHUNK] = {c.x, c.y, c.z, c.w};
        cur = vb[0];
        #pragma unroll
        for (int j = 0; j < CHUNK; ++j) {
            float x = vi[j], y = vt[j];
            float d = fabsf(x) - fabsf(y);
            elem = fmaf(d, d, elem);
            int b = vb[j];
            if (b != cur) {              // interior boundary (~0.25% of threads)
                atomicAdd(seg_in + cur, si);
                atomicAdd(seg_tg + cur, st);
                cur = b; si = 0.0f; st = 0.0f;
            }
            si += x; st += y;
        }
    }

    // --- wave segmented scan; sorted ids => segment test is id equality ---
    #pragma unroll
    for (int d = 1; d < 64; d <<= 1) {
        float o1 = __shfl_up(si, d);
        float o2 = __shfl_up(st, d);
        int  oid = __shfl_up(cur, d);
        if (lane >= d && oid == cur) { si += o1; st += o2; }
    }
    const int  nextId = __shfl_down(cur, 1);
    const bool isTail = (lane == 63) || (nextId != cur);
    if (isTail && cur >= 0) {
        atomicAdd(seg_in + cur, si);
        atomicAdd(seg_tg + cur, st);
    }

    // --- block-reduce elementwise loss -> 256 partial slots ---
    #pragma unroll
    for (int off = 32; off; off >>= 1) elem += __shfl_xor(elem, off);
    __shared__ float wsum[4];
    int wid = threadIdx.x >> 6;
    if (lane == 0) wsum[wid] = elem;
    __syncthreads();
    if (threadIdx.x == 0) {
        float s = wsum[0] + wsum[1] + wsum[2] + wsum[3];
        atomicAdd(elem_part + (blockIdx.x & (NPART - 1)), (double)s);
    }
}

__global__ __launch_bounds__(1024) void finalize_kernel(
        const float* __restrict__ seg_in, const float* __restrict__ seg_tg,
        const double* __restrict__ elem_part, float* __restrict__ out)
{
    const float4* s4 = (const float4*)seg_in;
    const float4* g4 = (const float4*)seg_tg;
    double acc = 0.0;
    for (int i = threadIdx.x; i < BSEG / 4; i += 1024) {
        float4 a = s4[i], b = g4[i];
        float d0 = a.x * a.x - b.x * b.x;
        float d1 = a.y * a.y - b.y * b.y;
        float d2 = a.z * a.z - b.z * b.z;
        float d3 = a.w * a.w - b.w * b.w;
        acc += (double)d0 * d0 + (double)d1 * d1 + (double)d2 * d2 + (double)d3 * d3;
    }
    if (threadIdx.x < NPART) acc += elem_part[threadIdx.x];
    #pragma unroll
    for (int off = 32; off; off >>= 1) acc += __shfl_xor(acc, off);
    __shared__ double wsum[16];
    int lane = threadIdx.x & 63, wid = threadIdx.x >> 6;
    if (lane == 0) wsum[wid] = acc;
    __syncthreads();
    if (threadIdx.x == 0) {
        double t = 0.0;
        #pragma unroll
        for (int w = 0; w < 16; ++w) t += wsum[w];
        out[0] = (float)t;
    }
}

extern "C" void kernel_launch(void* const* d_in, const int* in_sizes, int n_in,
                              void* d_out, int out_size, void* d_ws, size_t ws_size,
                              hipStream_t stream) {
    const float* in    = (const float*)d_in[0];
    const float* tg    = (const float*)d_in[1];
    const int*   batch = (const int*)d_in[2];
    const int n = in_sizes[0];

    float*  seg_in    = (float*)d_ws;
    float*  seg_tg    = seg_in + BSEG;
    double* elem_part = (double*)(seg_in + 2 * BSEG);
    float*  out       = (float*)d_out;

    hipMemsetAsync(d_ws, 0, WS_BYTES, stream);

    const int nthreads = n / CHUNK;                   // N divisible by 4
    const int blocks   = (nthreads + 255) / 256;
    main_pass<<<blocks, 256, 0, stream>>>(in, tg, batch, seg_in, seg_tg, elem_part, n);

    finalize_kernel<<<1, 1024, 0, stream>>>(seg_in, seg_tg, elem_part, out);
}

// Round 15
// 231.449 us; speedup vs baseline: 1.0029x; 1.0029x over previous
//
#include <hip/hip_runtime.h>

#define BSEG   16384
#define NPART  256
// ws layout: elem_part[NPART] f64 (2 KB) | seg_start[BSEG+1] i32 (~64 KB)
// total ~66.6 KB — well under the proven-fitting 133 KB layout.

__global__ __launch_bounds__(256) void seg_bounds(
        const int* __restrict__ batch, int n, int* __restrict__ seg_start)
{
    int s = blockIdx.x * 256 + threadIdx.x;
    if (s > BSEG) return;
    if (s == BSEG) { seg_start[s] = n; return; }
    int lo = 0, hi = n;                 // lower_bound: first idx with batch[idx] >= s
    while (lo < hi) {
        int mid = (lo + hi) >> 1;       // n = 20M, no overflow
        if (batch[mid] < s) lo = mid + 1; else hi = mid;
    }
    seg_start[s] = lo;                  // empty segments handled naturally
}

// One wave owns one segment: pure contiguous float4 streaming of in/tg,
// no batch reads, no scans, no segment atomics.
__global__ __launch_bounds__(256) void seg_sum(
        const float* __restrict__ in, const float* __restrict__ tg,
        const int* __restrict__ seg_start, double* __restrict__ elem_part)
{
    const int lane = threadIdx.x & 63;
    const int wid  = threadIdx.x >> 6;
    const int s    = blockIdx.x * 4 + wid;        // grid = BSEG/4 → s < BSEG

    const int lo = seg_start[s], hi = seg_start[s + 1];

    float si = 0.f, st = 0.f, elem = 0.f;

    // scalar head up to 16B alignment
    const int head = min(hi, (lo + 3) & ~3);
    int i = lo + lane;
    if (i < head) {
        float x = in[i], y = tg[i];
        si += x; st += y;
        float d = fabsf(x) - fabsf(y);
        elem = fmaf(d, d, elem);
    }
    // aligned float4 body: lane k reads 16B at head+16k — the m13 shape
    const int nb = (hi - head) >> 2;              // number of float4s
    for (int k = lane; k < nb; k += 64) {
        const int base = head + (k << 2);
        float4 a = *reinterpret_cast<const float4*>(in + base);
        float4 b = *reinterpret_cast<const float4*>(tg + base);
        si += a.x + a.y + a.z + a.w;
        st += b.x + b.y + b.z + b.w;
        float d0 = fabsf(a.x) - fabsf(b.x);
        float d1 = fabsf(a.y) - fabsf(b.y);
        float d2 = fabsf(a.z) - fabsf(b.z);
        float d3 = fabsf(a.w) - fabsf(b.w);
        elem = fmaf(d0, d0, elem); elem = fmaf(d1, d1, elem);
        elem = fmaf(d2, d2, elem); elem = fmaf(d3, d3, elem);
    }
    // scalar tail
    const int tail = head + (nb << 2);
    i = tail + lane;
    if (i < hi) {
        float x = in[i], y = tg[i];
        si += x; st += y;
        float d = fabsf(x) - fabsf(y);
        elem = fmaf(d, d, elem);
    }

    // wave reduction (64 lanes)
    #pragma unroll
    for (int off = 32; off; off >>= 1) {
        si   += __shfl_xor(si, off);
        st   += __shfl_xor(st, off);
        elem += __shfl_xor(elem, off);
    }

    __shared__ double wacc[4];
    if (lane == 0) {
        float d = si * si - st * st;              // f32, like the reference
        wacc[wid] = (double)d * (double)d + (double)elem;
    }
    __syncthreads();
    if (threadIdx.x == 0) {
        atomicAdd(elem_part + (blockIdx.x & (NPART - 1)),
                  wacc[0] + wacc[1] + wacc[2] + wacc[3]);
    }
}

__global__ __launch_bounds__(256) void finalize_kernel(
        const double* __restrict__ elem_part, float* __restrict__ out)
{
    double v = elem_part[threadIdx.x];
    #pragma unroll
    for (int off = 32; off; off >>= 1) v += __shfl_xor(v, off);
    __shared__ double wsum[4];
    int lane = threadIdx.x & 63, wid = threadIdx.x >> 6;
    if (lane == 0) wsum[wid] = v;
    __syncthreads();
    if (threadIdx.x == 0)
        out[0] = (float)(wsum[0] + wsum[1] + wsum[2] + wsum[3]);
}

extern "C" void kernel_launch(void* const* d_in, const int* in_sizes, int n_in,
                              void* d_out, int out_size, void* d_ws, size_t ws_size,
                              hipStream_t stream) {
    const float* in    = (const float*)d_in[0];
    const float* tg    = (const float*)d_in[1];
    const int*   batch = (const int*)d_in[2];
    const int n = in_sizes[0];

    double* elem_part = (double*)d_ws;
    int*    seg_start = (int*)((char*)d_ws + NPART * 8);
    float*  out       = (float*)d_out;

    hipMemsetAsync(d_ws, 0, NPART * 8, stream);   // only elem_part needs zeroing

    seg_bounds<<<(BSEG + 1 + 255) / 256, 256, 0, stream>>>(batch, n, seg_start);
    seg_sum<<<BSEG / 4, 256, 0, stream>>>(in, tg, seg_start, elem_part);
    finalize_kernel<<<1, 256, 0, stream>>>(elem_part, out);
}